// Round 2
// baseline (5313.042 us; speedup 1.0000x reference)
//
#include <hip/hip_runtime.h>
#include <math.h>

// Problem constants (from reference)
#define TB   4096      // batch
#define TK   20        // neighbors
#define TL   2         // layers
#define TD   256       // node feat dim
#define TFE  256       // edge feat dim
#define TT   100       // time dim
#define TE   356       // attn embed dim (D+T)
#define TKD  612       // key/value input dim (D+FE+T)
#define THD  178       // head dim (E/H, H=2)
#define TM   (TB*TK)   // 81920 neighbor rows

// ---------------------------------------------------------------------------
// Generic tiled f32 GEMM: C[M,N] = act(A[M,Kd] . W[N,Kd]^T + bias[N])
// GATHER mode: A row m = concat(node[rowidx[m]], mem[rowidx[m]]), Kd=512.
// Tile: BM=128, BN=64, BK=16, 256 threads, 8x4 outputs/thread.
// ---------------------------------------------------------------------------
template<bool GATHER>
__global__ __launch_bounds__(256) void gemm_kernel(
    const float* __restrict__ A, int lda,
    const float* __restrict__ A2,          // memory_table (gather mode)
    const int*   __restrict__ rowidx,      // gather row indices
    const float* __restrict__ W, int ldb,
    const float* __restrict__ bias,
    float* __restrict__ C, int ldc,
    int M, int N, int Kd, int relu)
{
    __shared__ float As[16][128];
    __shared__ float Bs[16][64];
    const int tid = threadIdx.x;
    const int m0 = blockIdx.y * 128;
    const int n0 = blockIdx.x * 64;
    const int tx = tid & 15, ty = tid >> 4;

    float acc[8][4];
#pragma unroll
    for (int i = 0; i < 8; i++)
#pragma unroll
        for (int j = 0; j < 4; j++) acc[i][j] = 0.f;

    const int arow = tid >> 1;          // 0..127
    const int akb  = (tid & 1) * 8;     // 0 or 8
    const int brow = tid >> 2;          // 0..63
    const int bkb  = (tid & 3) * 4;     // 0,4,8,12

    for (int k0 = 0; k0 < Kd; k0 += 16) {
        // stage A tile
        {
            const int m = m0 + arow;
            float v[8];
            if (m < M) {
                const int col = k0 + akb;
                if (GATHER) {
                    const int ri = rowidx[m];
                    // col block of 8 is 8-aligned; never straddles the 256 split
                    const float* src = (col < 256)
                        ? (A  + (size_t)ri * 256 + col)
                        : (A2 + (size_t)ri * 256 + (col - 256));
#pragma unroll
                    for (int c = 0; c < 8; c++) v[c] = src[c];
                } else {
#pragma unroll
                    for (int c = 0; c < 8; c++) {
                        const int cc = col + c;
                        v[c] = (cc < Kd) ? A[(size_t)m * lda + cc] : 0.f;
                    }
                }
            } else {
#pragma unroll
                for (int c = 0; c < 8; c++) v[c] = 0.f;
            }
#pragma unroll
            for (int c = 0; c < 8; c++) As[akb + c][arow] = v[c];
        }
        // stage W tile
        {
            const int n = n0 + brow;
            const int col = k0 + bkb;
#pragma unroll
            for (int c = 0; c < 4; c++) {
                const int cc = col + c;
                Bs[bkb + c][brow] = (n < N && cc < Kd) ? W[(size_t)n * ldb + cc] : 0.f;
            }
        }
        __syncthreads();
#pragma unroll
        for (int kk = 0; kk < 16; kk++) {
            float a[8], b[4];
#pragma unroll
            for (int i = 0; i < 8; i++) a[i] = As[kk][ty * 8 + i];
#pragma unroll
            for (int j = 0; j < 4; j++) b[j] = Bs[kk][tx * 4 + j];
#pragma unroll
            for (int i = 0; i < 8; i++)
#pragma unroll
                for (int j = 0; j < 4; j++) acc[i][j] += a[i] * b[j];
        }
        __syncthreads();
    }

#pragma unroll
    for (int i = 0; i < 8; i++) {
        const int m = m0 + ty * 8 + i;
        if (m >= M) continue;
#pragma unroll
        for (int j = 0; j < 4; j++) {
            const int n = n0 + tx * 4 + j;
            if (n >= N) continue;
            float v = acc[i][j] + (bias ? bias[n] : 0.f);
            if (relu) v = fmaxf(v, 0.f);
            C[(size_t)m * ldc + n] = v;
        }
    }
}

// ---------------------------------------------------------------------------
// Small elementwise / gather kernels
// ---------------------------------------------------------------------------
__global__ void transpose_pw_kernel(const float* __restrict__ pw, float* __restrict__ o)
{
    int idx = blockIdx.x * 256 + threadIdx.x;
    if (idx >= 256 * 512) return;
    int n = idx >> 9, j = idx & 511;      // o[n][j] = pw[j][n]
    o[idx] = pw[j * 256 + n];
}

__global__ void time_enc_src_kernel(const float* __restrict__ ts,
                                    const float* __restrict__ w,
                                    const float* __restrict__ b,
                                    float* __restrict__ o)
{
    int idx = blockIdx.x * 256 + threadIdx.x;
    if (idx >= TB * TT) return;
    int bb = idx / TT, t = idx - bb * TT;
    o[idx] = cosf(ts[bb] * w[t] + b[t]);
}

// fill k_in cols [256..612): edge feature gather + edge time encoding
__global__ void fill_kin_kernel(const float* __restrict__ ef,
                                const int*   __restrict__ eidx,
                                const float* __restrict__ et,
                                const float* __restrict__ w,
                                const float* __restrict__ b,
                                float* __restrict__ kin)
{
    int idx = blockIdx.x * 256 + threadIdx.x;
    if (idx >= TM * (TFE + TT)) return;
    int m = idx / (TFE + TT), c = idx - m * (TFE + TT);
    float v;
    if (c < TFE) v = ef[(size_t)eidx[m] * TFE + c];
    else { int t = c - TFE; v = cosf(et[m] * w[t] + b[t]); }
    kin[(size_t)m * TKD + TD + c] = v;
}

__global__ void build_qin_kernel(const float* __restrict__ cur,
                                 const float* __restrict__ ste,
                                 float* __restrict__ qin)
{
    int idx = blockIdx.x * 256 + threadIdx.x;
    if (idx >= TB * TE) return;
    int bb = idx / TE, c = idx - bb * TE;
    qin[idx] = (c < TD) ? cur[bb * TD + c] : ste[bb * TT + (c - TD)];
}

__global__ void build_fc1in_kernel(const float* __restrict__ ao,
                                   const float* __restrict__ cur,
                                   const int*   __restrict__ inv,
                                   float* __restrict__ o)
{
    int idx = blockIdx.x * 256 + threadIdx.x;
    if (idx >= TB * TKD) return;
    int bb = idx / TKD, c = idx - bb * TKD;
    float v;
    if (c < TE) v = inv[bb] ? 0.f : ao[bb * TE + c];
    else        v = cur[bb * TD + (c - TE)];
    o[idx] = v;
}

// ---------------------------------------------------------------------------
// Attention: one block per b; K=20 keys, H=2 heads, hd=178.
// ---------------------------------------------------------------------------
__global__ __launch_bounds__(256) void attn_kernel(
    const float* __restrict__ Q,    // [B,356]
    const float* __restrict__ Kt,   // [B*20,356]
    const float* __restrict__ V,    // [B*20,356]
    const int*   __restrict__ nbr,  // [B*20]
    float* __restrict__ ctx,        // [B,356]
    int*   __restrict__ inv)        // [B]
{
    const int b = blockIdx.x;
    const int tid = threadIdx.x;
    __shared__ float qrow[TE];
    __shared__ float sc[2 * TK];
    __shared__ float aw[2 * TK];
    __shared__ int   nb[TK];

    if (tid < TK) nb[tid] = nbr[b * TK + tid];
    for (int e = tid; e < TE; e += 256) qrow[e] = Q[(size_t)b * TE + e];
    __syncthreads();

    const int lane = tid & 63, wid = tid >> 6;
    const float scale = 0.074953262f;   // 1/sqrt(178)
    for (int p = wid; p < 2 * TK; p += 4) {
        const int h = p / TK, k = p - h * TK;
        const float* kr = Kt + (size_t)(b * TK + k) * TE + h * THD;
        const float* qr = qrow + h * THD;
        float s = 0.f;
        for (int d = lane; d < THD; d += 64) s += qr[d] * kr[d];
#pragma unroll
        for (int off = 32; off; off >>= 1) s += __shfl_down(s, off);
        if (lane == 0) sc[p] = s * scale;
    }
    __syncthreads();

    if (tid < 2) {
        const int h = tid;
        bool allm = true;
        for (int k = 0; k < TK; k++) allm = allm && (nb[k] == 0);
        if (tid == 0) inv[b] = allm ? 1 : 0;
        float s[TK];
        float mx = -1e30f;
        for (int k = 0; k < TK; k++) {
            bool masked = (nb[k] == 0) && !(allm && k == 0);
            s[k] = masked ? -1e9f : sc[h * TK + k];
            mx = fmaxf(mx, s[k]);
        }
        float sum = 0.f;
        for (int k = 0; k < TK; k++) { s[k] = expf(s[k] - mx); sum += s[k]; }
        const float r = 1.f / sum;
        for (int k = 0; k < TK; k++) aw[h * TK + k] = s[k] * r;
    }
    __syncthreads();

    for (int e = tid; e < TE; e += 256) {
        const int h = (e >= THD) ? 1 : 0;
        const float* awh = aw + h * TK;
        float s = 0.f;
#pragma unroll
        for (int k = 0; k < TK; k++) s += awh[k] * V[(size_t)(b * TK + k) * TE + e];
        ctx[(size_t)b * TE + e] = s;
    }
}

// ---------------------------------------------------------------------------
// Host launcher
// ---------------------------------------------------------------------------
extern "C" void kernel_launch(void* const* d_in, const int* in_sizes, int n_in,
                              void* d_out, int out_size, void* d_ws, size_t ws_size,
                              hipStream_t stream)
{
    const float* node = (const float*)d_in[0];
    const float* memt = (const float*)d_in[1];
    const float* ef   = (const float*)d_in[2];
    const int*   src  = (const int*)  d_in[3];
    const float* ts   = (const float*)d_in[4];
    const int*   nbrs = (const int*)  d_in[5];
    const int*   eidx = (const int*)  d_in[6];
    const float* etms = (const float*)d_in[7];
    const float* tw   = (const float*)d_in[8];
    const float* tbv  = (const float*)d_in[9];
    const float* pw   = (const float*)d_in[10];
    const float* pb   = (const float*)d_in[11];
    const float* Wq   = (const float*)d_in[12];
    const float* bq   = (const float*)d_in[13];
    const float* Wk   = (const float*)d_in[14];
    const float* bk   = (const float*)d_in[15];
    const float* Wv   = (const float*)d_in[16];
    const float* bv   = (const float*)d_in[17];
    const float* Wo   = (const float*)d_in[18];
    const float* bo   = (const float*)d_in[19];
    const float* f1W  = (const float*)d_in[20];
    const float* f1b  = (const float*)d_in[21];
    const float* f2W  = (const float*)d_in[22];
    const float* f2b  = (const float*)d_in[23];
    float* out = (float*)d_out;

    // workspace layout (f32) — total ~482 MB
    float* ws = (float*)d_ws;
    size_t off = 0;
    auto alloc = [&](size_t n) { float* p = ws + off; off += n; return p; };
    float* projWT  = alloc(256 * 512);
    float* srcte   = alloc((size_t)TB * TT);
    float* curA    = alloc((size_t)TB * TD);
    float* curB    = alloc((size_t)TB * TD);
    float* qin     = alloc((size_t)TB * TE);
    float* qbuf    = alloc((size_t)TB * TE);
    float* ctx     = alloc((size_t)TB * TE);
    float* aout    = alloc((size_t)TB * TE);
    float* fc1in   = alloc((size_t)TB * TKD);
    float* h1      = alloc((size_t)TB * TD);
    int*   inv     = (int*)alloc(TB);
    float* kin     = alloc((size_t)TM * TKD);
    float* Ktb     = alloc((size_t)TM * TE);
    float* Vb      = alloc((size_t)TM * TE);
    (void)ws_size; (void)in_sizes; (void)n_in; (void)out_size;

    auto gemm = [&](const float* A, int lda, const float* W, int ldb,
                    const float* bias, float* C, int ldc,
                    int M, int N, int Kd, int relu) {
        dim3 g((N + 63) / 64, (M + 127) / 128);
        gemm_kernel<false><<<g, 256, 0, stream>>>(A, lda, nullptr, nullptr,
                                                  W, ldb, bias, C, ldc, M, N, Kd, relu);
    };
    auto gemm_gather = [&](const int* ridx, const float* W, const float* bias,
                           float* C, int ldc, int M) {
        dim3 g(256 / 64, (M + 127) / 128);
        gemm_kernel<true><<<g, 256, 0, stream>>>(node, 256, memt, ridx,
                                                 W, 512, bias, C, ldc, M, 256, 512, 0);
    };

    // prologue
    transpose_pw_kernel<<<(256 * 512 + 255) / 256, 256, 0, stream>>>(pw, projWT);
    time_enc_src_kernel<<<(TB * TT + 255) / 256, 256, 0, stream>>>(ts, tw, tbv, srcte);
    gemm_gather(src, projWT, pb, curA, TD, TB);          // cur0 [B,256]

    const float* curp = curA;
    for (int l = 0; l < TL; ++l) {
        const int*   nbr_l  = nbrs + (size_t)l * TM;
        const int*   eidx_l = eidx + (size_t)l * TM;
        const float* et_l   = etms + (size_t)l * TM;

        // neighbor embeddings -> k_in[:, 0:256]
        gemm_gather(nbr_l, projWT, pb, kin, TKD, TM);
        fill_kin_kernel<<<((size_t)TM * (TFE + TT) + 255) / 256, 256, 0, stream>>>(
            ef, eidx_l, et_l, tw, tbv, kin);

        // K, V
        gemm(kin, TKD, Wk + (size_t)l * TE * TKD, TKD, bk + l * TE, Ktb, TE, TM, TE, TKD, 0);
        gemm(kin, TKD, Wv + (size_t)l * TE * TKD, TKD, bv + l * TE, Vb,  TE, TM, TE, TKD, 0);

        // Q
        build_qin_kernel<<<(TB * TE + 255) / 256, 256, 0, stream>>>(curp, srcte, qin);
        gemm(qin, TE, Wq + (size_t)l * TE * TE, TE, bq + l * TE, qbuf, TE, TB, TE, TE, 0);

        // attention
        attn_kernel<<<TB, 256, 0, stream>>>(qbuf, Ktb, Vb, nbr_l, ctx, inv);

        // output proj + merge MLP
        gemm(ctx, TE, Wo + (size_t)l * TE * TE, TE, bo + l * TE, aout, TE, TB, TE, TE, 0);
        build_fc1in_kernel<<<(TB * TKD + 255) / 256, 256, 0, stream>>>(aout, curp, inv, fc1in);
        gemm(fc1in, TKD, f1W + (size_t)l * TD * TKD, TKD, f1b + l * TD, h1, TD, TB, TD, TKD, 1);
        float* dst = (l == 0) ? curB : out;
        gemm(h1, TD, f2W + (size_t)l * TD * TD, TD, f2b + l * TD, dst, TD, TB, TD, TD, 0);
        curp = dst;
    }
}